// Round 22
// baseline (38.629 us; speedup 1.0000x reference)
//
#include <hip/hip_runtime.h>
#include <math.h>

#define HH 192
#define WW 192
#define NPIX (HH * WW)
#define SCALE 0.25f            // head_dim(16)^-0.5
#define C1 0.36067376f         // SCALE * log2(e)

// attention tile: 4 rows x 8 cols; halo 10 rows x 14 cols, cols padded to 16
#define HR 10
#define HC 14
#define NSLOT 160              // 10 * 16 n-slots (pads cx=14,15 are masked)
#define VOFF 160               // dword offset of V region (mC first)
#define AOFF 5280              // dword offset of A-tile region (after V)

typedef __attribute__((ext_vector_type(8))) _Float16 f16x8;
typedef __attribute__((ext_vector_type(4))) _Float16 f16x4;
typedef __attribute__((ext_vector_type(4))) float f32x4;

#if __has_builtin(__builtin_amdgcn_exp2f)
#define EXP2(x) __builtin_amdgcn_exp2f(x)
#else
#define EXP2(x) exp2f(x)
#endif

#define MFMA16(a, b, c) __builtin_amdgcn_mfma_f32_16x16x16f16((a), (b), (c), 0, 0, 0)

static __device__ __forceinline__ short f16s(float f)
{
    _Float16 h = (_Float16)f;
    short s; __builtin_memcpy(&s, &h, 2); return s;
}

static __device__ __forceinline__ unsigned int pack_f16(float a, float b)
{
    unsigned short ul = (unsigned short)f16s(a);
    unsigned short uh = (unsigned short)f16s(b);
    return ((unsigned int)uh << 16) | ul;
}

// ---------------------------------------------------------------------------
// Kernel 1: Q/K/V projection via MFMA — A-fragments DIRECT from global x
// (lane=pixel, k=cin is exactly NCHW's layout: 16 consecutive pixels per
// 16-lane group = 64B segments). x-loads issued BEFORE weight staging so
// their latency hides under it; only wTs staged in LDS (48 iters vs 64,
// no xT round-trip/transpose). B-side stays LDS-staged (r9's failure was
// B-side global wT thrash, not A-side direct reads).
// Tail block (blockIdx == NPIX/64) preps wp into wT rows 192..255.
// ---------------------------------------------------------------------------
__global__ __launch_bounds__(256) void qkv_mfma(
    const float* __restrict__ x,
    const float* __restrict__ wq, const float* __restrict__ wk,
    const float* __restrict__ wv, const float* __restrict__ wp,
    unsigned int* __restrict__ qg, unsigned int* __restrict__ kg,
    unsigned int* __restrict__ vg, short* __restrict__ wT)
{
    const int t = threadIdx.x;

    if (blockIdx.x == NPIX / 64) {
        #pragma unroll
        for (int i = 0; i < 16; ++i) {
            const int idx = i * 256 + t;      // 0..4095
            const int n = idx >> 6, k = idx & 63;
            wT[(192 + n) * 64 + k] = f16s(wp[k * 64 + n]);
        }
        return;
    }

    __shared__ short wTs[192 * 72];          // weights only (27 KB)
    const int px0 = blockIdx.x * 64;
    const int lane = t & 63;
    const int wid  = t >> 6;                  // M-tile (16 px)
    const int l15  = lane & 15;
    const int kg4  = lane >> 4;
    const int px   = px0 + wid * 16 + l15;

    // ---- issue A-side x loads FIRST (latency hides under weight staging)
    float xa[16];
    #pragma unroll
    for (int e = 0; e < 16; ++e) {
        const int cin = (e >> 3) * 32 + kg4 * 8 + (e & 7);   // ks*32+kg4*8+e
        xa[e] = x[(size_t)cin * NPIX + px];
    }

    // ---- stage wTs for q,k,v: w[k][n] f32 -> wTs[n][k] f16
    #pragma unroll
    for (int m = 0; m < 3; ++m) {
        const float* ws = (m == 0) ? wq : (m == 1) ? wk : wv;
        #pragma unroll
        for (int r = 0; r < 16; ++r) {
            const int idx = r * 256 + t;      // 0..4095
            const int k = idx >> 6, n = idx & 63;
            wTs[(m * 64 + n) * 72 + k] = f16s(ws[k * 64 + n]);
        }
    }
    __syncthreads();

    // convert A-fragments
    f16x8 afrag[2];
    #pragma unroll
    for (int ks = 0; ks < 2; ++ks)
        #pragma unroll
        for (int e = 0; e < 8; ++e)
            afrag[ks][e] = (_Float16)xa[ks * 8 + e];

    f32x4 acc[12];
    #pragma unroll
    for (int nt = 0; nt < 12; ++nt) acc[nt] = (f32x4){0.f, 0.f, 0.f, 0.f};

    #pragma unroll
    for (int ks = 0; ks < 2; ++ks) {
        #pragma unroll
        for (int nt = 0; nt < 12; ++nt) {
            const f16x8 b = *reinterpret_cast<const f16x8*>(
                &wTs[(nt * 16 + l15) * 72 + ks * 32 + kg4 * 8]);
            acc[nt] = __builtin_amdgcn_mfma_f32_16x16x32_f16(afrag[ks], b, acc[nt], 0, 0, 0);
        }
    }

    #pragma unroll
    for (int nt = 0; nt < 12; ++nt) {
        unsigned int* dst = (nt < 4) ? qg : (nt < 8) ? kg : vg;
        const int dwb = (nt & 3) * 8 + (l15 >> 1);
        #pragma unroll
        for (int r = 0; r < 4; ++r) {
            const float val = acc[nt][r];
            const float par = __shfl_xor(val, 1, 64);
            if (!(lane & 1)) {
                const int opx = px0 + wid * 16 + kg4 * 4 + r;
                dst[(size_t)opx * 32 + dwb] = pack_f16(val, par);
            }
        }
    }
}

// ---------------------------------------------------------------------------
// Kernel 2: MFMA neighborhood attention + fused MFMA output projection.
// EXACT r20 champion (35.7 us): 4 waves, wave = head, both q-tiles per wave,
// per-nt fused QK->softmax->PV, dedicated A-region, swapped-operand proj
// with coalesced stores. (r21's setprio was neutral -> dropped.)
// LDS: mC[160] + V[5120] + A[1152] dw = 25.7 KB.
// ---------------------------------------------------------------------------
__global__ __launch_bounds__(256) void attn_proj(
    const unsigned int* __restrict__ qg,
    const unsigned int* __restrict__ kg,
    const unsigned int* __restrict__ vg,
    const float* __restrict__ sims,
    const short* __restrict__ wT,
    float* __restrict__ out)
{
    __shared__ unsigned int smem[AOFF + 1152];    // mC | V | A

    const int bid = blockIdx.x;
    const int tl = (bid & 7) * 144 + (bid >> 3);  // XCD swizzle (1152 = 8*144)
    const int ty = tl / 24, tx = tl - ty * 24;    // 48 x 24 tiles
    const int Y0 = ty * 4, X0 = tx * 8;
    int hy0 = Y0 - 3; hy0 = hy0 < 0 ? 0 : (hy0 > HH - HR ? HH - HR : hy0);
    int hx0 = X0 - 3; hx0 = hx0 < 0 ? 0 : (hx0 > WW - HC ? WW - HC : hx0);
    const int t = threadIdx.x;

    // ---- stage V (row-major [n][16] f16 per head, zero-filled pads) + mC
    #pragma unroll
    for (int i = 0; i < 5; ++i) {
        const int idx = i * 256 + t;              // 0..1279
        const int n = idx >> 3, u = idx & 7;
        const int ry = n >> 4, cx = n & 15;
        uint4 vv = make_uint4(0u, 0u, 0u, 0u);
        if (cx < HC) {
            const int np = (hy0 + ry) * WW + hx0 + cx;
            vv = *reinterpret_cast<const uint4*>(vg + (size_t)np * 32 + u * 4);
        }
        const int h = u >> 1, hf = u & 1;
        *reinterpret_cast<uint4*>(smem + VOFF + h * 1280 + n * 8 + hf * 4) = vv;
    }
    if (t < NSLOT) {
        const int ry = t >> 4, cx = t & 15;
        float m = 0.f;
        if (cx < HC) {
            const int np = (hy0 + ry) * WW + hx0 + cx;
            const int sbase = (Y0 >> 4) * 12 + (X0 >> 4);   // block-uniform
            m = sims[np * 144 + sbase];
        }
        reinterpret_cast<float*>(smem)[t] = m * C1;
    }
    __syncthreads();

    const int h    = t >> 6;                  // wave = head
    const int lane = t & 63;
    const int l15  = lane & 15;
    const int kg4  = lane >> 4;
    const float* mC = reinterpret_cast<const float*>(smem);

    // ---- V^T A-fragments via hardware transpose read (linear 8B/lane)
    const unsigned vbyte = (unsigned)(uintptr_t)smem + VOFF * 4
                         + h * 5120 + lane * 8;
    f16x4 vf[10];
#define TRREAD(I, IMM) \
    asm volatile("ds_read_b64_tr_b16 %0, %1 offset:" IMM \
                 : "=v"(vf[I]) : "v"(vbyte))
    TRREAD(0, "0");    TRREAD(1, "512");  TRREAD(2, "1024"); TRREAD(3, "1536");
    TRREAD(4, "2048"); TRREAD(5, "2560"); TRREAD(6, "3072"); TRREAD(7, "3584");
    TRREAD(8, "4096"); TRREAD(9, "4608");
#undef TRREAD

    // ---- K A-fragments (qt-invariant): lane col cx = l15 of halo row nt
    const unsigned int* kgp = kg + (size_t)(hy0 * WW + hx0 + l15) * 32
                            + h * 8 + kg4 * 2;
    f16x4 kf[10];
    #pragma unroll
    for (int nt = 0; nt < 10; ++nt)
        kf[nt] = *reinterpret_cast<const f16x4*>(kgp + (size_t)nt * (WW * 32));

    // tr-reads must land before PV; single wait, then both qt passes
    asm volatile("s_waitcnt lgkmcnt(0)" ::: "memory");
    __builtin_amdgcn_sched_barrier(0);

    short* A = reinterpret_cast<short*>(smem + AOFF);

    #pragma unroll 1
    for (int qt = 0; qt < 2; ++qt) {
        const int q = qt * 16 + l15;
        const int qry = q >> 3, qcx = q & 7;
        const int y = Y0 + qry, x = X0 + qcx;
        int sy = y - 3; sy = sy < 0 ? 0 : (sy > HH - 7 ? HH - 7 : sy);
        int sx = x - 3; sx = sx < 0 ? 0 : (sx > WW - 7 ? WW - 7 : sx);
        const int wy = sy - hy0, wx = sx - hx0;

        // Q^T B-fragment from global (lane col q, k-rows d = kg4*4..+3)
        const f16x4 qb = *reinterpret_cast<const f16x4*>(
            qg + (size_t)(y * WW + x) * 32 + h * 8 + kg4 * 2);

        // masks for D rows (cx = kg4*4 + e)
        float vx[4];
        #pragma unroll
        for (int rr = 0; rr < 4; ++rr)
            vx[rr] = ((unsigned)(kg4 * 4 + rr - wx) < 7u) ? 1.f : 0.f;

        // per-nt fused QK^T -> softmax -> PV (no-max softmax; logits bounded)
        float Ss = 0.f;
        f32x4 o = (f32x4){0.f, 0.f, 0.f, 0.f};
        #pragma unroll
        for (int nt = 0; nt < 10; ++nt) {
            const f32x4 s = MFMA16(kf[nt], qb, ((f32x4){0.f, 0.f, 0.f, 0.f}));
            const f32x4 mcv = *reinterpret_cast<const f32x4*>(
                mC + nt * 16 + kg4 * 4);
            const float vy = ((unsigned)(nt - wy) < 7u) ? 1.f : 0.f;
            float pf[4];
            #pragma unroll
            for (int e = 0; e < 4; ++e) {
                const float u = s[e] * mcv[e];       // dot * m * SCALE*log2e
                const float p = EXP2(u);
                const float pv = p * vy * vx[e];
                Ss += pv;
                pf[e] = pv * mcv[e];                 // P^T = pv * m * C1
            }
            const f16x4 pt = (f16x4){(_Float16)pf[0], (_Float16)pf[1],
                                     (_Float16)pf[2], (_Float16)pf[3]};
            o = MFMA16(vf[nt], pt, o);
        }
        Ss += __shfl_xor(Ss, 16, 64);
        Ss += __shfl_xor(Ss, 32, 64);
        const float invq = 1.f / (C1 * Ss);

        // immediate A-tile store (A region does NOT alias mC/V)
        const f16x4 ov = (f16x4){
            (_Float16)(o[0] * invq), (_Float16)(o[1] * invq),
            (_Float16)(o[2] * invq), (_Float16)(o[3] * invq)};
        *reinterpret_cast<f16x4*>(&A[q * 72 + h * 16 + kg4 * 4]) = ov;
    }
    __syncthreads();

    // ---- fused projection, swapped operands (r20-proven):
    // out^T[c][px] = sum_k wp^T[c][k] * A_att[px][k]
    // D: col = px (l15), row = cout (kg4*4+reg) -> coalesced scalar stores.
    const short* A_lds = reinterpret_cast<const short*>(smem + AOFF);

    f16x8 aw[2];
    #pragma unroll
    for (int ks = 0; ks < 2; ++ks)
        aw[ks] = *reinterpret_cast<const f16x8*>(
            &wT[(192 + h * 16 + l15) * 64 + ks * 32 + kg4 * 8]);

    #pragma unroll
    for (int pxt = 0; pxt < 2; ++pxt) {
        f32x4 pacc = (f32x4){0.f, 0.f, 0.f, 0.f};
        #pragma unroll
        for (int ks = 0; ks < 2; ++ks) {
            const f16x8 bx = *reinterpret_cast<const f16x8*>(
                &A_lds[(pxt * 16 + l15) * 72 + ks * 32 + kg4 * 8]);
            pacc = __builtin_amdgcn_mfma_f32_16x16x32_f16(aw[ks], bx, pacc, 0, 0, 0);
        }
        const int p = pxt * 16 + l15;             // tile pixel (D col)
        const int gy = Y0 + (p >> 3), gx = X0 + (p & 7);
        #pragma unroll
        for (int r = 0; r < 4; ++r) {
            const int c = h * 16 + kg4 * 4 + r;   // cout (D row)
            out[(size_t)c * NPIX + gy * WW + gx] = pacc[r];
        }
    }
}

// ---------------------------------------------------------------------------
extern "C" void kernel_launch(void* const* d_in, const int* in_sizes, int n_in,
                              void* d_out, int out_size, void* d_ws, size_t ws_size,
                              hipStream_t stream)
{
    const float* x    = (const float*)d_in[0];
    const float* sims = (const float*)d_in[1];
    const float* wq   = (const float*)d_in[2];
    const float* wk   = (const float*)d_in[3];
    const float* wv   = (const float*)d_in[4];
    const float* wp   = (const float*)d_in[5];
    float* out = (float*)d_out;

    unsigned int* qg = (unsigned int*)d_ws;            // f16x2 [NPIX][32]
    unsigned int* kg = qg + (size_t)NPIX * 32;
    unsigned int* vg = kg + (size_t)NPIX * 32;
    short* wT = (short*)(vg + (size_t)NPIX * 32);      // f16 [256][64]

    qkv_mfma<<<NPIX / 64 + 1, 256, 0, stream>>>(x, wq, wk, wv, wp, qg, kg, vg, wT);
    attn_proj<<<1152, 256, 0, stream>>>(qg, kg, vg, sims, wT, out);
}

// Round 23
// 35.803 us; speedup vs baseline: 1.0789x; 1.0789x over previous
//
#include <hip/hip_runtime.h>
#include <math.h>

#define HH 192
#define WW 192
#define NPIX (HH * WW)
#define SCALE 0.25f            // head_dim(16)^-0.5
#define C1 0.36067376f         // SCALE * log2(e)

// attention tile: 4 rows x 8 cols; halo 10 rows x 14 cols, cols padded to 16
#define HR 10
#define HC 14
#define NSLOT 160              // 10 * 16 n-slots (pads cx=14,15 are masked)
#define VOFF 160               // dword offset of V region (mC first)
#define AOFF 5280              // dword offset of A-tile region (after V)

typedef __attribute__((ext_vector_type(8))) _Float16 f16x8;
typedef __attribute__((ext_vector_type(4))) _Float16 f16x4;
typedef __attribute__((ext_vector_type(4))) float f32x4;

#if __has_builtin(__builtin_amdgcn_exp2f)
#define EXP2(x) __builtin_amdgcn_exp2f(x)
#else
#define EXP2(x) exp2f(x)
#endif

#define MFMA16(a, b, c) __builtin_amdgcn_mfma_f32_16x16x16f16((a), (b), (c), 0, 0, 0)

static __device__ __forceinline__ short f16s(float f)
{
    _Float16 h = (_Float16)f;
    short s; __builtin_memcpy(&s, &h, 2); return s;
}

static __device__ __forceinline__ unsigned int pack_f16(float a, float b)
{
    unsigned short ul = (unsigned short)f16s(a);
    unsigned short uh = (unsigned short)f16s(b);
    return ((unsigned int)uh << 16) | ul;
}

// ---------------------------------------------------------------------------
// Kernel 1: Q/K/V projection via MFMA — 32 px/block for 2x TLP (1152 blocks,
// 18-20 waves/CU vs 9 at 64 px; r18 proved staging-amortization isn't
// binding, so bet on latency hiding). Waves split the N axis: wave =
// (m = w&1 M-tile, nh = w>>1 N-half), 12 MFMA each, all waves active.
// LDS (32+192)x72 shorts = 31.5 KB -> 5 blocks/CU, single-round.
// Tail block (blockIdx == NPIX/32) preps wp into wT rows 192..255.
// ---------------------------------------------------------------------------
__global__ __launch_bounds__(256) void qkv_mfma(
    const float* __restrict__ x,
    const float* __restrict__ wq, const float* __restrict__ wk,
    const float* __restrict__ wv, const float* __restrict__ wp,
    unsigned int* __restrict__ qg, unsigned int* __restrict__ kg,
    unsigned int* __restrict__ vg, short* __restrict__ wT)
{
    const int t = threadIdx.x;

    if (blockIdx.x == NPIX / 32) {
        #pragma unroll
        for (int i = 0; i < 16; ++i) {
            const int idx = i * 256 + t;      // 0..4095
            const int n = idx >> 6, k = idx & 63;
            wT[(192 + n) * 64 + k] = f16s(wp[k * 64 + n]);
        }
        return;
    }

    __shared__ short lds[(32 + 192) * 72];   // xT[32][72] then wTs[192][72]
    short* xT = lds;
    short* wTs = lds + 32 * 72;
    const int px0 = blockIdx.x * 32;

    // stage xT: 32 px x 64 cin (coalesced f32 reads)
    #pragma unroll
    for (int r = 0; r < 8; ++r) {
        const int idx = r * 256 + t;          // 0..2047
        const int cin = idx >> 5, pxl = idx & 31;
        xT[pxl * 72 + cin] = f16s(x[(size_t)cin * NPIX + px0 + pxl]);
    }
    // stage wTs for q,k,v: w[k][n] f32 -> wTs[n][k] f16
    #pragma unroll
    for (int m = 0; m < 3; ++m) {
        const float* ws = (m == 0) ? wq : (m == 1) ? wk : wv;
        #pragma unroll
        for (int r = 0; r < 16; ++r) {
            const int idx = r * 256 + t;      // 0..4095
            const int k = idx >> 6, n = idx & 63;
            wTs[(m * 64 + n) * 72 + k] = f16s(ws[k * 64 + n]);
        }
    }
    __syncthreads();

    const int lane = t & 63;
    const int w    = t >> 6;                  // wave
    const int mt   = w & 1;                   // M-tile (16 px)
    const int nh   = w >> 1;                  // N-half (6 N-tiles)
    const int l15  = lane & 15;
    const int kg4  = lane >> 4;

    f32x4 acc[6];
    #pragma unroll
    for (int n6 = 0; n6 < 6; ++n6) acc[n6] = (f32x4){0.f, 0.f, 0.f, 0.f};

    #pragma unroll
    for (int ks = 0; ks < 2; ++ks) {
        const f16x8 a = *reinterpret_cast<const f16x8*>(
            &xT[(mt * 16 + l15) * 72 + ks * 32 + kg4 * 8]);
        #pragma unroll
        for (int n6 = 0; n6 < 6; ++n6) {
            const int nt = nh * 6 + n6;
            const f16x8 b = *reinterpret_cast<const f16x8*>(
                &wTs[(nt * 16 + l15) * 72 + ks * 32 + kg4 * 8]);
            acc[n6] = __builtin_amdgcn_mfma_f32_16x16x32_f16(a, b, acc[n6], 0, 0, 0);
        }
    }

    #pragma unroll
    for (int n6 = 0; n6 < 6; ++n6) {
        const int nt = nh * 6 + n6;
        unsigned int* dst = (nt < 4) ? qg : (nt < 8) ? kg : vg;
        const int dwb = (nt & 3) * 8 + (l15 >> 1);
        #pragma unroll
        for (int r = 0; r < 4; ++r) {
            const float val = acc[n6][r];
            const float par = __shfl_xor(val, 1, 64);
            if (!(lane & 1)) {
                const int opx = px0 + mt * 16 + kg4 * 4 + r;
                dst[(size_t)opx * 32 + dwb] = pack_f16(val, par);
            }
        }
    }
}

// ---------------------------------------------------------------------------
// Kernel 2: MFMA neighborhood attention + fused MFMA output projection.
// EXACT r20 champion (35.7 us): 4 waves, wave = head, both q-tiles per wave,
// per-nt fused QK->softmax->PV, dedicated A-region, swapped-operand proj
// with coalesced stores. LDS: mC[160] + V[5120] + A[1152] dw = 25.7 KB.
// ---------------------------------------------------------------------------
__global__ __launch_bounds__(256) void attn_proj(
    const unsigned int* __restrict__ qg,
    const unsigned int* __restrict__ kg,
    const unsigned int* __restrict__ vg,
    const float* __restrict__ sims,
    const short* __restrict__ wT,
    float* __restrict__ out)
{
    __shared__ unsigned int smem[AOFF + 1152];    // mC | V | A

    const int bid = blockIdx.x;
    const int tl = (bid & 7) * 144 + (bid >> 3);  // XCD swizzle (1152 = 8*144)
    const int ty = tl / 24, tx = tl - ty * 24;    // 48 x 24 tiles
    const int Y0 = ty * 4, X0 = tx * 8;
    int hy0 = Y0 - 3; hy0 = hy0 < 0 ? 0 : (hy0 > HH - HR ? HH - HR : hy0);
    int hx0 = X0 - 3; hx0 = hx0 < 0 ? 0 : (hx0 > WW - HC ? WW - HC : hx0);
    const int t = threadIdx.x;

    // ---- stage V (row-major [n][16] f16 per head, zero-filled pads) + mC
    #pragma unroll
    for (int i = 0; i < 5; ++i) {
        const int idx = i * 256 + t;              // 0..1279
        const int n = idx >> 3, u = idx & 7;
        const int ry = n >> 4, cx = n & 15;
        uint4 vv = make_uint4(0u, 0u, 0u, 0u);
        if (cx < HC) {
            const int np = (hy0 + ry) * WW + hx0 + cx;
            vv = *reinterpret_cast<const uint4*>(vg + (size_t)np * 32 + u * 4);
        }
        const int h = u >> 1, hf = u & 1;
        *reinterpret_cast<uint4*>(smem + VOFF + h * 1280 + n * 8 + hf * 4) = vv;
    }
    if (t < NSLOT) {
        const int ry = t >> 4, cx = t & 15;
        float m = 0.f;
        if (cx < HC) {
            const int np = (hy0 + ry) * WW + hx0 + cx;
            const int sbase = (Y0 >> 4) * 12 + (X0 >> 4);   // block-uniform
            m = sims[np * 144 + sbase];
        }
        reinterpret_cast<float*>(smem)[t] = m * C1;
    }
    __syncthreads();

    const int h    = t >> 6;                  // wave = head
    const int lane = t & 63;
    const int l15  = lane & 15;
    const int kg4  = lane >> 4;
    const float* mC = reinterpret_cast<const float*>(smem);

    // ---- V^T A-fragments via hardware transpose read (linear 8B/lane)
    const unsigned vbyte = (unsigned)(uintptr_t)smem + VOFF * 4
                         + h * 5120 + lane * 8;
    f16x4 vf[10];
#define TRREAD(I, IMM) \
    asm volatile("ds_read_b64_tr_b16 %0, %1 offset:" IMM \
                 : "=v"(vf[I]) : "v"(vbyte))
    TRREAD(0, "0");    TRREAD(1, "512");  TRREAD(2, "1024"); TRREAD(3, "1536");
    TRREAD(4, "2048"); TRREAD(5, "2560"); TRREAD(6, "3072"); TRREAD(7, "3584");
    TRREAD(8, "4096"); TRREAD(9, "4608");
#undef TRREAD

    // ---- K A-fragments (qt-invariant): lane col cx = l15 of halo row nt
    const unsigned int* kgp = kg + (size_t)(hy0 * WW + hx0 + l15) * 32
                            + h * 8 + kg4 * 2;
    f16x4 kf[10];
    #pragma unroll
    for (int nt = 0; nt < 10; ++nt)
        kf[nt] = *reinterpret_cast<const f16x4*>(kgp + (size_t)nt * (WW * 32));

    // tr-reads must land before PV; single wait, then both qt passes
    asm volatile("s_waitcnt lgkmcnt(0)" ::: "memory");
    __builtin_amdgcn_sched_barrier(0);

    short* A = reinterpret_cast<short*>(smem + AOFF);

    #pragma unroll 1
    for (int qt = 0; qt < 2; ++qt) {
        const int q = qt * 16 + l15;
        const int qry = q >> 3, qcx = q & 7;
        const int y = Y0 + qry, x = X0 + qcx;
        int sy = y - 3; sy = sy < 0 ? 0 : (sy > HH - 7 ? HH - 7 : sy);
        int sx = x - 3; sx = sx < 0 ? 0 : (sx > WW - 7 ? WW - 7 : sx);
        const int wy = sy - hy0, wx = sx - hx0;

        // Q^T B-fragment from global (lane col q, k-rows d = kg4*4..+3)
        const f16x4 qb = *reinterpret_cast<const f16x4*>(
            qg + (size_t)(y * WW + x) * 32 + h * 8 + kg4 * 2);

        // masks for D rows (cx = kg4*4 + e)
        float vx[4];
        #pragma unroll
        for (int rr = 0; rr < 4; ++rr)
            vx[rr] = ((unsigned)(kg4 * 4 + rr - wx) < 7u) ? 1.f : 0.f;

        // per-nt fused QK^T -> softmax -> PV (no-max softmax; logits bounded)
        float Ss = 0.f;
        f32x4 o = (f32x4){0.f, 0.f, 0.f, 0.f};
        #pragma unroll
        for (int nt = 0; nt < 10; ++nt) {
            const f32x4 s = MFMA16(kf[nt], qb, ((f32x4){0.f, 0.f, 0.f, 0.f}));
            const f32x4 mcv = *reinterpret_cast<const f32x4*>(
                mC + nt * 16 + kg4 * 4);
            const float vy = ((unsigned)(nt - wy) < 7u) ? 1.f : 0.f;
            float pf[4];
            #pragma unroll
            for (int e = 0; e < 4; ++e) {
                const float u = s[e] * mcv[e];       // dot * m * SCALE*log2e
                const float p = EXP2(u);
                const float pv = p * vy * vx[e];
                Ss += pv;
                pf[e] = pv * mcv[e];                 // P^T = pv * m * C1
            }
            const f16x4 pt = (f16x4){(_Float16)pf[0], (_Float16)pf[1],
                                     (_Float16)pf[2], (_Float16)pf[3]};
            o = MFMA16(vf[nt], pt, o);
        }
        Ss += __shfl_xor(Ss, 16, 64);
        Ss += __shfl_xor(Ss, 32, 64);
        const float invq = 1.f / (C1 * Ss);

        // immediate A-tile store (A region does NOT alias mC/V)
        const f16x4 ov = (f16x4){
            (_Float16)(o[0] * invq), (_Float16)(o[1] * invq),
            (_Float16)(o[2] * invq), (_Float16)(o[3] * invq)};
        *reinterpret_cast<f16x4*>(&A[q * 72 + h * 16 + kg4 * 4]) = ov;
    }
    __syncthreads();

    // ---- fused projection, swapped operands (r20-proven):
    // out^T[c][px] = sum_k wp^T[c][k] * A_att[px][k]
    // D: col = px (l15), row = cout (kg4*4+reg) -> coalesced scalar stores.
    const short* A_lds = reinterpret_cast<const short*>(smem + AOFF);

    f16x8 aw[2];
    #pragma unroll
    for (int ks = 0; ks < 2; ++ks)
        aw[ks] = *reinterpret_cast<const f16x8*>(
            &wT[(192 + h * 16 + l15) * 64 + ks * 32 + kg4 * 8]);

    #pragma unroll
    for (int pxt = 0; pxt < 2; ++pxt) {
        f32x4 pacc = (f32x4){0.f, 0.f, 0.f, 0.f};
        #pragma unroll
        for (int ks = 0; ks < 2; ++ks) {
            const f16x8 bx = *reinterpret_cast<const f16x8*>(
                &A_lds[(pxt * 16 + l15) * 72 + ks * 32 + kg4 * 8]);
            pacc = __builtin_amdgcn_mfma_f32_16x16x32_f16(aw[ks], bx, pacc, 0, 0, 0);
        }
        const int p = pxt * 16 + l15;             // tile pixel (D col)
        const int gy = Y0 + (p >> 3), gx = X0 + (p & 7);
        #pragma unroll
        for (int r = 0; r < 4; ++r) {
            const int c = h * 16 + kg4 * 4 + r;   // cout (D row)
            out[(size_t)c * NPIX + gy * WW + gx] = pacc[r];
        }
    }
}

// ---------------------------------------------------------------------------
extern "C" void kernel_launch(void* const* d_in, const int* in_sizes, int n_in,
                              void* d_out, int out_size, void* d_ws, size_t ws_size,
                              hipStream_t stream)
{
    const float* x    = (const float*)d_in[0];
    const float* sims = (const float*)d_in[1];
    const float* wq   = (const float*)d_in[2];
    const float* wk   = (const float*)d_in[3];
    const float* wv   = (const float*)d_in[4];
    const float* wp   = (const float*)d_in[5];
    float* out = (float*)d_out;

    unsigned int* qg = (unsigned int*)d_ws;            // f16x2 [NPIX][32]
    unsigned int* kg = qg + (size_t)NPIX * 32;
    unsigned int* vg = kg + (size_t)NPIX * 32;
    short* wT = (short*)(vg + (size_t)NPIX * 32);      // f16 [256][64]

    qkv_mfma<<<NPIX / 32 + 1, 256, 0, stream>>>(x, wq, wk, wv, wp, qg, kg, vg, wT);
    attn_proj<<<1152, 256, 0, stream>>>(qg, kg, vg, sims, wT, out);
}